// Round 1
// baseline (3603.163 us; speedup 1.0000x reference)
//
#include <hip/hip_runtime.h>
#include <hip/hip_bf16.h>

// P_Model: 64-step linear recurrence state_{t+1} = P @ state_t on MI355X.
// Dense part: h_{t+1} = 0.9*h_t + Q@h_t + DT*M*(CA·x_t),  Q = DT*W + DT*U Vᵀ + M cb Z  (bf16 MFMA)
// Low-rank part: zh = Z@h;  con = B1*zh;  x_{t+1} = A x + B*zh   (f32 exact)

#define N_H   4096
#define BATCH 512
#define STEPS 64
#define TRAJ_ROWS 4098

typedef __attribute__((ext_vector_type(8))) short bf16x8;
typedef __attribute__((ext_vector_type(4))) float f32x4;
typedef unsigned int u32;
typedef unsigned short u16;

static const size_t CONBASE = (size_t)STEPS * TRAJ_ROWS * BATCH; // 134283264

__device__ inline u16 f2bf(float f) {
    union { float f; u32 u; } v; v.f = f;
    u32 r = v.u + 0x7fffu + ((v.u >> 16) & 1u); // RNE
    return (u16)(r >> 16);
}

__device__ inline void gload_lds16(const void* g, void* l) {
    __builtin_amdgcn_global_load_lds(
        (const __attribute__((address_space(1))) u32*)g,
        (__attribute__((address_space(3))) u32*)l, 16, 0, 0);
}

// ---------------------------------------------------------------------------
// Build Q (bf16): Q[i][j] = DT*W[i][j] + DT*sum_r U[i][r]V[j][r] + M[i]*cb*Z[j]
// ---------------------------------------------------------------------------
__global__ __launch_bounds__(256) void build_q(
    const float* __restrict__ W, const float* __restrict__ U,
    const float* __restrict__ V, const float* __restrict__ Mv,
    const float* __restrict__ Zv, const float* __restrict__ Cv,
    const float* __restrict__ Bv, u16* __restrict__ Qb)
{
    size_t base = ((size_t)blockIdx.x * 256 + threadIdx.x) * 8;
    int i = (int)(base >> 12);
    int j = (int)(base & 4095);
    float cb = Cv[0] * Bv[0] + Cv[1] * Bv[1];
    float micb = Mv[i] * cb;
    const float* Ui = U + (size_t)i * 4;
    float u0 = Ui[0], u1 = Ui[1], u2 = Ui[2], u3 = Ui[3];
    float4 w0 = *(const float4*)(W + base);
    float4 w1 = *(const float4*)(W + base + 4);
    float wv[8] = {w0.x, w0.y, w0.z, w0.w, w1.x, w1.y, w1.z, w1.w};
    u16 q[8];
#pragma unroll
    for (int e = 0; e < 8; ++e) {
        int jj = j + e;
        float4 vv = *(const float4*)(V + (size_t)jj * 4);
        float uv = u0 * vv.x + u1 * vv.y + u2 * vv.z + u3 * vv.w;
        float qq = 0.1f * wv[e] + 0.1f * uv + micb * Zv[jj];
        q[e] = f2bf(qq);
    }
    uint4 pk;
    pk.x = (u32)q[0] | ((u32)q[1] << 16);
    pk.y = (u32)q[2] | ((u32)q[3] << 16);
    pk.z = (u32)q[4] | ((u32)q[5] << 16);
    pk.w = (u32)q[6] | ((u32)q[7] << 16);
    *(uint4*)(Qb + base) = pk;
}

// ---------------------------------------------------------------------------
// zred_transpose: per 64x64 tile of h_t (f32 [4096][512]):
//  - hbT[n][k] = bf16(h[k][n])      (transposed operand for GEMM B)
//  - zh_t[n]  += sum_k Z[k]*h[k][n] (atomics)
// grid (8 n-tiles, 64 k-tiles), 256 threads
// ---------------------------------------------------------------------------
__global__ __launch_bounds__(256) void zred_transpose(
    const float* __restrict__ h, const float* __restrict__ Zv,
    u16* __restrict__ hbT, float* __restrict__ zh_t)
{
    __shared__ u16 LT[64 * 72];   // padded rows: 72 elems = 144 B (bank-friendly)
    __shared__ float zloc[64];
    int tid = threadIdx.x;
    int n0 = blockIdx.x * 64, k0 = blockIdx.y * 64;
    if (tid < 64) zloc[tid] = 0.f;
    __syncthreads();
    int nl = (tid & 15) * 4;
    int kt = tid >> 4;
    float za0 = 0, za1 = 0, za2 = 0, za3 = 0;
#pragma unroll
    for (int p = 0; p < 4; ++p) {
        int kl = p * 16 + kt;
        int k = k0 + kl;
        float4 v = *(const float4*)(h + (size_t)k * BATCH + n0 + nl);
        float zk = Zv[k];
        za0 += zk * v.x; za1 += zk * v.y; za2 += zk * v.z; za3 += zk * v.w;
        LT[(nl + 0) * 72 + kl] = f2bf(v.x);
        LT[(nl + 1) * 72 + kl] = f2bf(v.y);
        LT[(nl + 2) * 72 + kl] = f2bf(v.z);
        LT[(nl + 3) * 72 + kl] = f2bf(v.w);
    }
    atomicAdd(&zloc[nl + 0], za0);
    atomicAdd(&zloc[nl + 1], za1);
    atomicAdd(&zloc[nl + 2], za2);
    atomicAdd(&zloc[nl + 3], za3);
    __syncthreads();
    if (tid < 64) atomicAdd(zh_t + n0 + tid, zloc[tid]);
#pragma unroll
    for (int w = 0; w < 2; ++w) {
        int nrow = (tid >> 3) + w * 32;
        int kc = tid & 7;
        const u16* p = &LT[nrow * 72 + kc * 8];
        ushort4 lo = *(const ushort4*)p;
        ushort4 hi = *(const ushort4*)(p + 4);
        u16* dst = hbT + (size_t)(n0 + nrow) * 4096 + k0 + kc * 8;
        *(ushort4*)dst = lo;
        *(ushort4*)(dst + 4) = hi;
    }
}

// ---------------------------------------------------------------------------
// gemm_step: h_{t+1} = Q@h_t + 0.9*h_t + 0.1*M*(CA·x_t); writes h_out + traj[t+1].
// Block (0,0) also does the tiny step-t work (con_t, x_{t+1}, traj[t] x-rows).
// Tile 64x64, BK=64, 4 waves (2x2), mfma 16x16x32 bf16.
// LDS staged via global_load_lds(16B) with XOR-chunk pre-swizzled sources so
// ds_read_b128 fragment reads are 2-way-bank-conflict-free.
// ---------------------------------------------------------------------------
__global__ __launch_bounds__(256) void gemm_step(
    const u16* __restrict__ Qb, const u16* __restrict__ hbT,
    const float* __restrict__ h_in, float* __restrict__ h_out,
    float* __restrict__ outp, const float* __restrict__ Mv,
    const float* __restrict__ Cv, const float* __restrict__ Av,
    const float* __restrict__ Bv, float* __restrict__ xbuf,
    const float* __restrict__ zh, int t)
{
    __shared__ char lds[16384];   // As: [0,8K) ; Bs: [8K,16K)
    const int tid = threadIdx.x;

    // ---- tiny per-step work (zh[t] is complete: producer kernel already done)
    if (blockIdx.x == 0 && blockIdx.y == 0) {
        float A00 = Av[0], A01 = Av[1], A10 = Av[2], A11 = Av[3];
        float B0 = Bv[0], B1 = Bv[1];
        const float* xt = xbuf + (size_t)t * 1024;
        float* xn = xbuf + (size_t)(t + 1) * 1024;
        size_t tb = (size_t)t * TRAJ_ROWS * BATCH;
        for (int c = tid; c < BATCH; c += 256) {
            float z = zh[t * BATCH + c];
            float x0c = xt[c], x1c = xt[BATCH + c];
            outp[CONBASE + (size_t)t * BATCH + c] = B1 * z;
            outp[tb + c] = x0c;
            outp[tb + BATCH + c] = x1c;
            xn[c]         = A00 * x0c + A01 * x1c + B0 * z;
            xn[BATCH + c] = A10 * x0c + A11 * x1c + B1 * z;
        }
    }

    const int lane = tid & 63, wid = tid >> 6;
    const int wr = wid >> 1, wc = wid & 1;
    const int m0 = blockIdx.y * 64, n0 = blockIdx.x * 64;
    const int rsub = lane >> 3;              // row within 8-row staging group
    const int csel = (lane & 7) ^ rsub;      // pre-swizzled 16B chunk select
    const u16* Abase = Qb + (size_t)m0 * 4096;
    const u16* Bbase = hbT + (size_t)n0 * 4096;
    const int s0 = wid * 2;

    f32x4 acc[2][2] = {};

    for (int ktile = 0; ktile < 64; ++ktile) {
        const int kcol = ktile * 64;
#pragma unroll
        for (int q = 0; q < 2; ++q) {
            int s = s0 + q;
            int row = s * 8 + rsub;
            gload_lds16(Abase + (size_t)row * 4096 + kcol + csel * 8, lds + s * 1024);
            gload_lds16(Bbase + (size_t)row * 4096 + kcol + csel * 8, lds + 8192 + s * 1024);
        }
        asm volatile("s_waitcnt vmcnt(0)" ::: "memory");
        __syncthreads();
#pragma unroll
        for (int ks = 0; ks < 2; ++ks) {
            bf16x8 af[2], bfr[2];
#pragma unroll
            for (int m = 0; m < 2; ++m) {
                int row = wr * 32 + m * 16 + (lane & 15);
                int kbyte = ks * 64 + (lane >> 4) * 16;
                af[m] = *(const bf16x8*)(lds + row * 128 + (kbyte ^ ((row & 7) << 4)));
            }
#pragma unroll
            for (int n = 0; n < 2; ++n) {
                int row = wc * 32 + n * 16 + (lane & 15);
                int kbyte = ks * 64 + (lane >> 4) * 16;
                bfr[n] = *(const bf16x8*)(lds + 8192 + row * 128 + (kbyte ^ ((row & 7) << 4)));
            }
#pragma unroll
            for (int m = 0; m < 2; ++m)
#pragma unroll
                for (int n = 0; n < 2; ++n)
                    acc[m][n] = __builtin_amdgcn_mfma_f32_16x16x32_bf16(
                        af[m], bfr[n], acc[m][n], 0, 0, 0);
        }
        __syncthreads();
    }

    // ---- epilogue: f32 identity path + rank-1 P21·x, write h_out and traj[t+1]
    float CA0 = Cv[0] * Av[0] + Cv[1] * Av[2];
    float CA1 = Cv[0] * Av[1] + Cv[1] * Av[3];
    const float* xt = xbuf + (size_t)t * 1024;
    size_t trajb = (size_t)(t + 1) * TRAJ_ROWS * BATCH;
#pragma unroll
    for (int m = 0; m < 2; ++m) {
#pragma unroll
        for (int n = 0; n < 2; ++n) {
            int gcol = n0 + wc * 32 + n * 16 + (lane & 15);
            float x0c = xt[gcol], x1c = xt[BATCH + gcol];
            float xterm = CA0 * x0c + CA1 * x1c;
#pragma unroll
            for (int r = 0; r < 4; ++r) {
                int grow = m0 + wr * 32 + m * 16 + (lane >> 4) * 4 + r;
                float val = acc[m][n][r]
                          + 0.9f * h_in[(size_t)grow * BATCH + gcol]
                          + 0.1f * Mv[grow] * xterm;
                h_out[(size_t)grow * BATCH + gcol] = val;
                outp[trajb + (size_t)(grow + 2) * BATCH + gcol] = val;
            }
        }
    }
}

// tiny work for the last step (no GEMM follows it)
__global__ __launch_bounds__(512) void tiny_last(
    float* __restrict__ outp, float* __restrict__ xbuf,
    const float* __restrict__ zh, const float* __restrict__ Av,
    const float* __restrict__ Bv, int t)
{
    int c = threadIdx.x;
    float A00 = Av[0], A01 = Av[1], A10 = Av[2], A11 = Av[3];
    float B0 = Bv[0], B1 = Bv[1];
    const float* xt = xbuf + (size_t)t * 1024;
    float* xn = xbuf + (size_t)(t + 1) * 1024;
    size_t tb = (size_t)t * TRAJ_ROWS * BATCH;
    float z = zh[t * BATCH + c];
    float x0c = xt[c], x1c = xt[BATCH + c];
    outp[CONBASE + (size_t)t * BATCH + c] = B1 * z;
    outp[tb + c] = x0c;
    outp[tb + BATCH + c] = x1c;
    xn[c]         = A00 * x0c + A01 * x1c + B0 * z;
    xn[BATCH + c] = A10 * x0c + A11 * x1c + B1 * z;
}

extern "C" void kernel_launch(void* const* d_in, const int* in_sizes, int n_in,
                              void* d_out, int out_size, void* d_ws, size_t ws_size,
                              hipStream_t stream)
{
    (void)in_sizes; (void)n_in; (void)out_size; (void)ws_size;
    const float* x0 = (const float*)d_in[0];
    const float* x1 = (const float*)d_in[1];
    const float* h0 = (const float*)d_in[2];
    const float* Av = (const float*)d_in[3];
    const float* Bv = (const float*)d_in[4];
    const float* Cv = (const float*)d_in[5];
    const float* Mv = (const float*)d_in[6];
    const float* Zv = (const float*)d_in[7];
    const float* Uv = (const float*)d_in[8];
    const float* Vv = (const float*)d_in[9];
    const float* Wv = (const float*)d_in[10];
    float* outp = (float*)d_out;

    char* ws = (char*)d_ws;
    const size_t OFF_Q   = 0;                       // 32 MB  bf16 Q
    const size_t OFF_HF0 = OFF_Q   + 33554432;      // 8 MB   f32 h ping
    const size_t OFF_HF1 = OFF_HF0 + 8388608;       // 8 MB   f32 h pong
    const size_t OFF_HBT = OFF_HF1 + 8388608;       // 4 MB   bf16 h^T
    const size_t OFF_XB  = OFF_HBT + 4194304;       // 65*1024 f32 x-states
    const size_t OFF_ZH  = OFF_XB  + 266240;        // 64*512 f32 zh

    u16*   Qb   = (u16*)(ws + OFF_Q);
    float* hf0  = (float*)(ws + OFF_HF0);
    float* hf1  = (float*)(ws + OFF_HF1);
    u16*   hbT  = (u16*)(ws + OFF_HBT);
    float* xbuf = (float*)(ws + OFF_XB);
    float* zh   = (float*)(ws + OFF_ZH);

    hipMemsetAsync(zh, 0, STEPS * BATCH * sizeof(float), stream);
    hipMemcpyAsync(xbuf, x0, BATCH * sizeof(float), hipMemcpyDeviceToDevice, stream);
    hipMemcpyAsync(xbuf + BATCH, x1, BATCH * sizeof(float), hipMemcpyDeviceToDevice, stream);
    // traj[0] h-part = h0
    hipMemcpyAsync(outp + 2 * BATCH, h0, (size_t)N_H * BATCH * sizeof(float),
                   hipMemcpyDeviceToDevice, stream);

    build_q<<<8192, 256, 0, stream>>>(Wv, Uv, Vv, Mv, Zv, Cv, Bv, Qb);

    for (int t = 0; t < STEPS; ++t) {
        const float* hsrc = (t == 0) ? h0 : ((t & 1) ? hf1 : hf0);
        zred_transpose<<<dim3(8, 64), 256, 0, stream>>>(hsrc, Zv, hbT, zh + t * BATCH);
        if (t < STEPS - 1) {
            float* hdst = ((t + 1) & 1) ? hf1 : hf0;
            gemm_step<<<dim3(8, 64), 256, 0, stream>>>(
                Qb, hbT, hsrc, hdst, outp, Mv, Cv, Av, Bv, xbuf, zh, t);
        } else {
            tiny_last<<<1, 512, 0, stream>>>(outp, xbuf, zh, Av, Bv, t);
        }
    }
}